// Round 1
// baseline (41.850 us; speedup 1.0000x reference)
//
#include <hip/hip_runtime.h>
#include <math.h>

#define BS   64
#define NW   8
#define NK   10
#define NP   16
#define NT   20
#define NN   4096
#define LOG2PI 1.8378770664093453f

__device__ __constant__ int d_wpix[NW] = {0, 2, 4, 6, 9, 12, 15, 19};

__global__ __launch_bounds__(256) void mdn_row_kernel(
    const float* __restrict__ mu,
    const float* __restrict__ sigma,
    const float* __restrict__ pi,
    const float* __restrict__ neg,
    const float* __restrict__ pos,
    const int* __restrict__ p_wh,
    const int* __restrict__ p_cap,
    float* __restrict__ rowres)
{
    __shared__ float s_negx[NN];
    __shared__ float s_negy[NN];
    __shared__ unsigned int s_dbits[NN];
    __shared__ unsigned int s_hist[256];
    __shared__ unsigned int s_wsum[4];
    __shared__ float s_red[8];
    __shared__ float s_posx[NP], s_posy[NP];
    __shared__ float s_mu0[NK], s_mu1[NK], s_is0[NK], s_is1[NK], s_ck[NK];
    __shared__ unsigned int s_bucket;
    __shared__ unsigned int s_below;
    __shared__ int s_tie;
    __shared__ float s_dmin;

    const int row  = blockIdx.x;       // 0 .. BS*NW-1
    const int b    = row / NW;
    const int w    = row % NW;
    const int tid  = threadIdx.x;
    const int lane = tid & 63;
    const int wid  = tid >> 6;

    // ---- stage negatives for this batch row (raw, un-reversed) ----
    const float2* negp = (const float2*)(neg + (size_t)b * NN * 2);
    for (int n = tid; n < NN; n += 256) {
        float2 v = negp[n];
        s_negx[n] = v.x;
        s_negy[n] = v.y;
    }
    // ---- stage the 16 positives for this waypoint ----
    if (tid < NP) {
        const float* pp = pos + (((size_t)b * NP + tid) * NT + d_wpix[w]) * 2;
        s_posx[tid] = pp[0];
        s_posy[tid] = pp[1];
    }
    // ---- mixture precompute (tiny; serial on thread 0) ----
    if (tid == 0) {
        const float* pib = pi + ((size_t)b * NW + w) * NK;
        float m = pib[0];
        for (int k = 1; k < NK; ++k) m = fmaxf(m, pib[k]);
        float se = 0.f;
        for (int k = 0; k < NK; ++k) se += expf(pib[k] - m);
        float lse = m + logf(se);
        const float* mub = mu    + ((size_t)b * NW + w) * NK * 2;
        const float* sgb = sigma + ((size_t)b * NW + w) * NK * 2;
        for (int k = 0; k < NK; ++k) {
            float s0 = sgb[2*k], s1 = sgb[2*k + 1];
            s_mu0[k] = mub[2*k]; s_mu1[k] = mub[2*k + 1];
            s_is0[k] = 1.0f / s0; s_is1[k] = 1.0f / s1;
            s_ck[k]  = (pib[k] - lse) - logf(s0) - logf(s1) - LOG2PI;
        }
        s_tie = 0;
    }
    __syncthreads();

    // ---- distances: dist[n] = sqrt(min_p |pos_p - neg_n|^2) ----
    // (coordinate reversal cancels in the distance; ignore it here)
    float lmin = INFINITY;
    for (int n = tid; n < NN; n += 256) {
        float nx = s_negx[n], ny = s_negy[n];
        float best = INFINITY;
        #pragma unroll
        for (int p = 0; p < NP; ++p) {
            float dx = s_posx[p] - nx;
            float dy = s_posy[p] - ny;
            float r  = dx * dx + dy * dy;
            best = fminf(best, r);
        }
        float dd = sqrtf(best);      // monotone: sqrt(min) == min(sqrt)
        s_dbits[n] = __float_as_uint(dd);
        lmin = fminf(lmin, dd);
    }
    // block min reduce (for softmax stabilization)
    #pragma unroll
    for (int off = 32; off; off >>= 1) lmin = fminf(lmin, __shfl_down(lmin, off, 64));
    if (lane == 0) s_red[wid] = lmin;
    __syncthreads();
    if (tid == 0) s_dmin = fminf(fminf(s_red[0], s_red[1]), fminf(s_red[2], s_red[3]));
    __syncthreads();

    // ---- radix select: exact k-th smallest (bit pattern) ----
    const int cap = *p_cap;
    const bool do_sel = (cap > 0 && cap < NN);
    unsigned int Tbits = 0xFFFFFFFFu;
    int need = 0;                       // ties at Tbits to include
    if (do_sel) {
        unsigned long long prefix = 0;  // decided high bytes (as value)
        int remaining = cap;
        for (int pos8 = 3; pos8 >= 0; --pos8) {
            s_hist[tid] = 0;
            __syncthreads();
            const int shift = pos8 * 8;
            for (int n = tid; n < NN; n += 256) {
                unsigned int u = s_dbits[n];
                if (((unsigned long long)u >> (shift + 8)) == prefix)
                    atomicAdd(&s_hist[(u >> shift) & 0xFFu], 1u);
            }
            __syncthreads();
            // exclusive scan of 256 bins across the block
            unsigned int cnt = s_hist[tid];
            unsigned int v = cnt;
            #pragma unroll
            for (int off = 1; off < 64; off <<= 1) {
                unsigned int o = __shfl_up(v, off, 64);
                if (lane >= off) v += o;
            }
            if (lane == 63) s_wsum[wid] = v;
            __syncthreads();
            unsigned int wbase = 0;
            for (int i = 0; i < wid; ++i) wbase += s_wsum[i];
            unsigned int incl = v + wbase;
            unsigned int excl = incl - cnt;
            if (excl < (unsigned int)remaining && (unsigned int)remaining <= incl) {
                s_bucket = (unsigned int)tid;
                s_below  = excl;
            }
            __syncthreads();
            remaining -= (int)s_below;
            prefix = (prefix << 8) | (unsigned long long)s_bucket;
            __syncthreads();
        }
        Tbits = (unsigned int)prefix;
        need  = ((int)(cap)) - (cap - /*remaining after loop*/ 0); // placeholder fixed below
        need  = 0; // replaced just after (kept explicit for clarity)
        // 'remaining' after the loop = number of elements equal to Tbits we must take
        need = remaining;
    }
    __syncthreads();

    // ---- weighted mixture accumulation over selected negatives ----
    const int wh = *p_wh;
    const float dmin = s_dmin;
    float accZ = 0.f, accS = 0.f;
    for (int n = tid; n < NN; n += 256) {
        unsigned int u = s_dbits[n];
        bool inc;
        if (!do_sel) {
            inc = true;
        } else {
            inc = (u < Tbits);
            if (u == Tbits) {
                int idx = atomicAdd(&s_tie, 1);
                inc = (idx < need);
            }
        }
        if (inc) {
            float dd = __uint_as_float(u);
            float e  = expf(dmin - dd);          // softmax numerator (stabilized)
            // reversal matters here: model order vs raw negative order
            float x0 = wh ? s_negy[n] : s_negx[n];
            float x1 = wh ? s_negx[n] : s_negy[n];
            float a[NK];
            float m = -INFINITY;
            #pragma unroll
            for (int k = 0; k < NK; ++k) {
                float z0 = (x0 - s_mu0[k]) * s_is0[k];
                float z1 = (x1 - s_mu1[k]) * s_is1[k];
                float ak = s_ck[k] - 0.5f * (z0 * z0 + z1 * z1);
                a[k] = ak;
                m = fmaxf(m, ak);
            }
            float se = 0.f;
            #pragma unroll
            for (int k = 0; k < NK; ++k) se += expf(a[k] - m);
            float lp = m + logf(se);
            accZ += e;
            accS += e * lp;
        }
    }
    #pragma unroll
    for (int off = 32; off; off >>= 1) {
        accZ += __shfl_down(accZ, off, 64);
        accS += __shfl_down(accS, off, 64);
    }
    if (lane == 0) { s_red[wid] = accZ; s_red[4 + wid] = accS; }
    __syncthreads();
    if (tid == 0) {
        float Z = (s_red[0] + s_red[1]) + (s_red[2] + s_red[3]);
        float S = (s_red[4] + s_red[5]) + (s_red[6] + s_red[7]);
        rowres[row] = S / Z;
    }
}

__global__ void mdn_finalize_kernel(const float* __restrict__ rowres,
                                    float* __restrict__ out)
{
    int b = threadIdx.x;
    if (b < BS) {
        float s = 0.f;
        #pragma unroll
        for (int w = 0; w < NW; ++w) s += rowres[b * NW + w];
        out[b] = -s * (1.0f / NW);
    }
}

extern "C" void kernel_launch(void* const* d_in, const int* in_sizes, int n_in,
                              void* d_out, int out_size, void* d_ws, size_t ws_size,
                              hipStream_t stream)
{
    const float* mu    = (const float*)d_in[0];
    const float* sigma = (const float*)d_in[1];
    const float* pi    = (const float*)d_in[2];
    const float* neg   = (const float*)d_in[3];
    const float* pos   = (const float*)d_in[4];
    const int*   wh    = (const int*)d_in[5];
    const int*   cap   = (const int*)d_in[6];
    float* rowres = (float*)d_ws;   // BS*NW floats = 2 KB scratch
    float* out    = (float*)d_out;

    mdn_row_kernel<<<BS * NW, 256, 0, stream>>>(mu, sigma, pi, neg, pos, wh, cap, rowres);
    mdn_finalize_kernel<<<1, 64, 0, stream>>>(rowres, out);
}

// Round 2
// 25.530 us; speedup vs baseline: 1.6393x; 1.6393x over previous
//
#include <hip/hip_runtime.h>
#include <math.h>

#define BS   64
#define NW   8
#define NK   10
#define NP   16
#define NT   20
#define NN   4096
#define NTHREADS 512
#define NWAVES   (NTHREADS / 64)
#define EPT      (NN / NTHREADS)      // elements per thread = 8
#define LOG2PI 1.8378770664093453f

__device__ __constant__ int d_wpix[NW] = {0, 2, 4, 6, 9, 12, 15, 19};

__global__ __launch_bounds__(NTHREADS) void mdn_row_kernel(
    const float* __restrict__ mu,
    const float* __restrict__ sigma,
    const float* __restrict__ pi,
    const float* __restrict__ neg,
    const float* __restrict__ pos,
    const int* __restrict__ p_wh,
    const int* __restrict__ p_cap,
    float* __restrict__ rowres)
{
    __shared__ float s_negx[NN];
    __shared__ float s_negy[NN];
    __shared__ unsigned int s_dbits[NN];
    __shared__ unsigned int s_hist[NN];          // radix hist; reused as selection list
    __shared__ unsigned int s_wsum[NWAVES];
    __shared__ float s_red[2 * NWAVES];
    __shared__ float s_posx[NP], s_posy[NP];
    __shared__ float s_mu0[NK], s_mu1[NK], s_is0[NK], s_is1[NK], s_ck[NK];
    __shared__ float s_lse;
    __shared__ unsigned int s_bucket;
    __shared__ unsigned int s_below;
    __shared__ float s_dmin;

    const int row  = blockIdx.x;          // 0 .. BS*NW-1
    const int b    = row / NW;
    const int w    = row % NW;
    const int tid  = threadIdx.x;
    const int lane = tid & 63;
    const int wid  = tid >> 6;

    // ---- stage negatives (raw order; reversal cancels in distances) ----
    const float2* negp = (const float2*)(neg + (size_t)b * NN * 2);
    for (int n = tid; n < NN; n += NTHREADS) {
        float2 v = negp[n];
        s_negx[n] = v.x;
        s_negy[n] = v.y;
    }
    // ---- stage the 16 positives for this waypoint ----
    if (tid < NP) {
        const float* pp = pos + (((size_t)b * NP + tid) * NT + d_wpix[w]) * 2;
        s_posx[tid] = pp[0];
        s_posy[tid] = pp[1];
    }
    // ---- pi log-sum-exp (tiny, thread 0) ----
    if (tid == 0) {
        const float* pib = pi + ((size_t)b * NW + w) * NK;
        float m = pib[0];
        for (int k = 1; k < NK; ++k) m = fmaxf(m, pib[k]);
        float se = 0.f;
        for (int k = 0; k < NK; ++k) se += __expf(pib[k] - m);
        s_lse = m + __logf(se);
    }
    __syncthreads();
    // ---- per-component precompute, parallel over k ----
    if (tid < NK) {
        const float* pib = pi    + ((size_t)b * NW + w) * NK;
        const float* mub = mu    + ((size_t)b * NW + w) * NK * 2;
        const float* sgb = sigma + ((size_t)b * NW + w) * NK * 2;
        float s0 = sgb[2 * tid], s1 = sgb[2 * tid + 1];
        s_mu0[tid] = mub[2 * tid];
        s_mu1[tid] = mub[2 * tid + 1];
        s_is0[tid] = 1.0f / s0;
        s_is1[tid] = 1.0f / s1;
        s_ck[tid]  = (pib[tid] - s_lse) - __logf(s0) - __logf(s1) - LOG2PI;
    }

    // ---- distances: dist[n] = sqrt(min_p |pos_p - neg_n|^2) ----
    float lmin = INFINITY;
    for (int n = tid; n < NN; n += NTHREADS) {
        float nx = s_negx[n], ny = s_negy[n];
        float best = INFINITY;
        #pragma unroll
        for (int p = 0; p < NP; ++p) {
            float dx = s_posx[p] - nx;
            float dy = s_posy[p] - ny;
            best = fminf(best, dx * dx + dy * dy);
        }
        float dd = sqrtf(best);              // sqrt(min) == min(sqrt)
        s_dbits[n] = __float_as_uint(dd);
        lmin = fminf(lmin, dd);
    }
    #pragma unroll
    for (int off = 32; off; off >>= 1) lmin = fminf(lmin, __shfl_down(lmin, off, 64));
    if (lane == 0) s_red[wid] = lmin;
    __syncthreads();
    if (tid == 0) {
        float m = s_red[0];
        for (int i = 1; i < NWAVES; ++i) m = fminf(m, s_red[i]);
        s_dmin = m;
    }

    // ---- 3-pass radix select (12 + 12 + 8 bits) for exact k-th smallest ----
    const int cap = *p_cap;
    const bool do_sel = (cap > 0 && cap < NN);
    const int capEff = do_sel ? cap : NN;
    unsigned int Tbits = 0xFFFFFFFFu;
    int need = 0;
    if (do_sel) {
        unsigned int prefix = 0;
        int rem = cap;
        #pragma unroll
        for (int ps = 0; ps < 3; ++ps) {
            const int sh = (ps == 0) ? 20 : (ps == 1) ? 8 : 0;
            const int wd = (ps == 2) ? 8 : 12;
            const unsigned int nb = 1u << wd;
            for (int i = tid; i < (int)nb; i += NTHREADS) s_hist[i] = 0;
            __syncthreads();
            for (int n = tid; n < NN; n += NTHREADS) {
                unsigned int u = s_dbits[n];
                bool match = (ps == 0) || ((u >> (sh + wd)) == prefix);
                if (match) atomicAdd(&s_hist[(u >> sh) & (nb - 1u)], 1u);
            }
            __syncthreads();
            // block-wide ranking over nb bins
            const int bpt = ((int)nb + NTHREADS - 1) / NTHREADS;
            const int base = tid * bpt;
            unsigned int cnt = 0;
            for (int j = 0; j < bpt; ++j) {
                int bi = base + j;
                if (bi < (int)nb) cnt += s_hist[bi];
            }
            unsigned int v = cnt;
            #pragma unroll
            for (int off = 1; off < 64; off <<= 1) {
                unsigned int o = __shfl_up(v, off, 64);
                if (lane >= off) v += o;
            }
            if (lane == 63) s_wsum[wid] = v;
            __syncthreads();
            unsigned int wbase = 0;
            for (int i = 0; i < wid; ++i) wbase += s_wsum[i];
            unsigned int incl = v + wbase;
            unsigned int excl = incl - cnt;
            if (excl < (unsigned int)rem && (unsigned int)rem <= incl) {
                unsigned int run = excl;
                for (int j = 0; j < bpt; ++j) {
                    int bi = base + j;
                    if (bi >= (int)nb) break;
                    unsigned int c = s_hist[bi];
                    if (run < (unsigned int)rem && (unsigned int)rem <= run + c) {
                        s_bucket = (unsigned int)bi;
                        s_below  = run;
                        break;
                    }
                    run += c;
                }
            }
            __syncthreads();
            rem -= (int)s_below;
            prefix = (prefix << wd) | s_bucket;
        }
        Tbits = prefix;
        need  = rem;                     // ties at Tbits to include
    }
    __syncthreads();

    // ---- deterministic compaction of selected indices into s_hist ----
    unsigned int* s_sel = s_hist;
    unsigned int uu[EPT];
    int cntL = 0, cntT = 0;
    #pragma unroll
    for (int c = 0; c < EPT; ++c) {
        int n = c * NTHREADS + tid;
        unsigned int u = s_dbits[n];
        uu[c] = u;
        cntL += (u < Tbits) ? 1 : 0;
        cntT += (u == Tbits) ? 1 : 0;
    }
    {
        unsigned int packed = ((unsigned int)cntL << 16) | (unsigned int)cntT;
        unsigned int v = packed;
        #pragma unroll
        for (int off = 1; off < 64; off <<= 1) {
            unsigned int o = __shfl_up(v, off, 64);
            if (lane >= off) v += o;
        }
        if (lane == 63) s_wsum[wid] = v;
        __syncthreads();
        unsigned int wbase = 0;
        for (int i = 0; i < wid; ++i) wbase += s_wsum[i];
        unsigned int exclP = (v + wbase) - packed;
        int baseL = (int)(exclP >> 16);
        int baseT = (int)(exclP & 0xFFFFu);
        const int C1 = capEff - need;    // count strictly below threshold
        #pragma unroll
        for (int c = 0; c < EPT; ++c) {
            int n = c * NTHREADS + tid;
            unsigned int u = uu[c];
            if (u < Tbits) {
                s_sel[baseL++] = (unsigned int)n;
            } else if (u == Tbits) {
                if (baseT < need) s_sel[C1 + baseT] = (unsigned int)n;
                baseT++;
            }
        }
    }
    __syncthreads();

    // ---- dense weighted mixture accumulation over the capEff selected ----
    const int wh = *p_wh;
    const float dmin = s_dmin;
    float accZ = 0.f, accS = 0.f;
    for (int i = tid; i < capEff; i += NTHREADS) {
        int n = (int)s_sel[i];
        float dd = __uint_as_float(s_dbits[n]);
        float e  = __expf(dmin - dd);            // stabilized softmax numerator
        float x0 = wh ? s_negy[n] : s_negx[n];   // reversal matters vs mu/sigma
        float x1 = wh ? s_negx[n] : s_negy[n];
        float a[NK];
        float m = -INFINITY;
        #pragma unroll
        for (int k = 0; k < NK; ++k) {
            float z0 = (x0 - s_mu0[k]) * s_is0[k];
            float z1 = (x1 - s_mu1[k]) * s_is1[k];
            float ak = fmaf(z0 * z0 + z1 * z1, -0.5f, s_ck[k]);
            a[k] = ak;
            m = fmaxf(m, ak);
        }
        float se = 0.f;
        #pragma unroll
        for (int k = 0; k < NK; ++k) se += __expf(a[k] - m);
        float lp = m + __logf(se);
        accZ += e;
        accS += e * lp;
    }
    #pragma unroll
    for (int off = 32; off; off >>= 1) {
        accZ += __shfl_down(accZ, off, 64);
        accS += __shfl_down(accS, off, 64);
    }
    if (lane == 0) { s_red[wid] = accZ; s_red[NWAVES + wid] = accS; }
    __syncthreads();
    if (tid == 0) {
        float Z = 0.f, S = 0.f;
        for (int i = 0; i < NWAVES; ++i) { Z += s_red[i]; S += s_red[NWAVES + i]; }
        rowres[row] = S / Z;
    }
}

__global__ void mdn_finalize_kernel(const float* __restrict__ rowres,
                                    float* __restrict__ out)
{
    int b = threadIdx.x;
    if (b < BS) {
        float s = 0.f;
        #pragma unroll
        for (int w = 0; w < NW; ++w) s += rowres[b * NW + w];
        out[b] = -s * (1.0f / NW);
    }
}

extern "C" void kernel_launch(void* const* d_in, const int* in_sizes, int n_in,
                              void* d_out, int out_size, void* d_ws, size_t ws_size,
                              hipStream_t stream)
{
    const float* mu    = (const float*)d_in[0];
    const float* sigma = (const float*)d_in[1];
    const float* pi    = (const float*)d_in[2];
    const float* neg   = (const float*)d_in[3];
    const float* pos   = (const float*)d_in[4];
    const int*   wh    = (const int*)d_in[5];
    const int*   cap   = (const int*)d_in[6];
    float* rowres = (float*)d_ws;   // BS*NW floats scratch
    float* out    = (float*)d_out;

    mdn_row_kernel<<<BS * NW, NTHREADS, 0, stream>>>(mu, sigma, pi, neg, pos, wh, cap, rowres);
    mdn_finalize_kernel<<<1, 64, 0, stream>>>(rowres, out);
}

// Round 4
// 21.505 us; speedup vs baseline: 1.9461x; 1.1872x over previous
//
#include <hip/hip_runtime.h>
#include <math.h>

#define BS   64
#define NW   8
#define NK   10
#define NP   16
#define NT   20
#define NN   4096
#define NTH  512
#define NWAVES (NTH / 64)
#define EPT  (NN / NTH)               // 8 negatives per thread, register-resident
#define NBINS 4096                    // single 12-bit radix pass
#define CANDMAX 2048
#define LOG2PI 1.8378770664093453f
#define LOG2E  1.4426950408889634f
#define LN2    0.6931471805599453f

__device__ __constant__ int d_wpix[NW] = {0, 2, 4, 6, 9, 12, 15, 19};

__global__ __launch_bounds__(NTH, 4) void mdn_row_kernel(
    const float* __restrict__ mu,
    const float* __restrict__ sigma,
    const float* __restrict__ pi,
    const float* __restrict__ neg,
    const float* __restrict__ pos,
    const int* __restrict__ p_wh,
    const int* __restrict__ p_cap,
    float* __restrict__ rowres)
{
    __shared__ unsigned int s_hist[NBINS];   // 16KB; reused as sel arrays after select
    __shared__ unsigned int s_cand[CANDMAX]; // 8KB boundary-bucket candidates
    __shared__ float s_posx[NP], s_posy[NP];
    __shared__ float s_mu0[NK], s_mu1[NK], s_is0[NK], s_is1[NK], s_ck2[NK];
    __shared__ unsigned int s_wsum[NWAVES];
    __shared__ float s_red[2 * NWAVES];
    __shared__ unsigned int s_bucket, s_below, s_candcnt, s_P;
    __shared__ float s_dmin;

    const int row  = blockIdx.x;      // 0 .. BS*NW-1
    const int b    = row / NW;
    const int w    = row % NW;
    const int tid  = threadIdx.x;
    const int lane = tid & 63;
    const int wid  = tid >> 6;

    // ---------- phase 0: zero hist, stage positives, mixture constants ----------
    #pragma unroll
    for (int j = 0; j < NBINS / NTH; ++j) s_hist[tid + j * NTH] = 0;
    if (tid < NP) {
        const float* pp = pos + (((size_t)b * NP + tid) * NT + d_wpix[w]) * 2;
        s_posx[tid] = pp[0];
        s_posy[tid] = pp[1];
    }
    if (tid >= 64 && tid < 64 + NK) {          // wave 1: per-component precompute
        const int k = tid - 64;
        const float* pib = pi    + ((size_t)b * NW + w) * NK;
        const float* mub = mu    + ((size_t)b * NW + w) * NK * 2;
        const float* sgb = sigma + ((size_t)b * NW + w) * NK * 2;
        float m = pib[0];
        for (int j = 1; j < NK; ++j) m = fmaxf(m, pib[j]);
        float se = 0.f;
        for (int j = 0; j < NK; ++j) se += __expf(pib[j] - m);
        float lse = m + __logf(se);
        float s0 = sgb[2 * k], s1 = sgb[2 * k + 1];
        s_mu0[k] = mub[2 * k];
        s_mu1[k] = mub[2 * k + 1];
        s_is0[k] = 1.0f / s0;
        s_is1[k] = 1.0f / s1;
        s_ck2[k] = ((pib[k] - lse) - __logf(s0) - __logf(s1) - LOG2PI) * LOG2E;
    }
    if (tid == 32) s_candcnt = 0;
    __syncthreads();                                           // B1

    float px[NP], py[NP];
    #pragma unroll
    for (int p = 0; p < NP; ++p) { px[p] = s_posx[p]; py[p] = s_posy[p]; }

    // ---------- phase 1: distances (registers) + histogram ----------
    const float2* negp = (const float2*)(neg + (size_t)b * NN * 2);
    float nx[EPT], ny[EPT];
    unsigned int ub[EPT];
    float lmin = INFINITY;
    #pragma unroll
    for (int c = 0; c < EPT; ++c) {
        const int n = c * NTH + tid;
        float2 v = negp[n];
        nx[c] = v.x; ny[c] = v.y;
        float best = INFINITY;
        #pragma unroll
        for (int p = 0; p < NP; ++p) {
            float dx = px[p] - v.x;
            float dy = py[p] - v.y;
            best = fminf(best, fmaf(dx, dx, dy * dy));
        }
        float dd = sqrtf(best);        // sqrt(min) == min(sqrt); stay in ref domain
        ub[c] = __float_as_uint(dd);
        lmin = fminf(lmin, dd);
        atomicAdd(&s_hist[ub[c] >> 20], 1u);
    }
    #pragma unroll
    for (int off = 32; off; off >>= 1) lmin = fminf(lmin, __shfl_down(lmin, off, 64));
    if (lane == 0) s_red[wid] = lmin;
    __syncthreads();                                           // B2
    if (tid == 0) {
        float m = s_red[0];
        for (int i = 1; i < NWAVES; ++i) m = fminf(m, s_red[i]);
        s_dmin = m;
    }

    const int cap = *p_cap;
    const bool do_sel = (cap > 0 && cap < NN);
    const int wh = *p_wh;

    float accZ = 0.f, accS = 0.f;

    if (do_sel) {
        // ---------- phase 2: rank over 4096 bins, find boundary bucket ----------
        const int base = tid * (NBINS / NTH);
        unsigned int hv[NBINS / NTH];
        unsigned int cnt = 0;
        #pragma unroll
        for (int j = 0; j < NBINS / NTH; ++j) { hv[j] = s_hist[base + j]; cnt += hv[j]; }
        unsigned int v = cnt;
        #pragma unroll
        for (int off = 1; off < 64; off <<= 1) {
            unsigned int o = __shfl_up(v, off, 64);
            if (lane >= off) v += o;
        }
        if (lane == 63) s_wsum[wid] = v;
        __syncthreads();                                       // B3
        unsigned int wbase = 0;
        for (int i = 0; i < wid; ++i) wbase += s_wsum[i];
        const unsigned int incl = v + wbase;
        const unsigned int excl = incl - cnt;
        const unsigned int capu = (unsigned int)cap;
        if (excl < capu && capu <= incl) {
            unsigned int run = excl;
            #pragma unroll
            for (int j = 0; j < NBINS / NTH; ++j) {
                unsigned int c2 = hv[j];
                if (capu <= run + c2) { s_bucket = (unsigned int)(base + j); s_below = run; break; }
                run += c2;
            }
        }
        __syncthreads();                                       // B4
        const unsigned int B = s_bucket;

        // ---------- phase 3: compact boundary-bucket candidates ----------
        #pragma unroll
        for (int c = 0; c < EPT; ++c) {
            if ((ub[c] >> 20) == B) {
                unsigned int p0 = atomicAdd(&s_candcnt, 1u);
                if (p0 < CANDMAX)
                    s_cand[p0] = (ub[c] << 12) | (unsigned int)(c * NTH + tid);
            }
        }
        __syncthreads();                                       // B5

        // ---------- phase 4: exact rank among candidates (packed keys distinct) ----------
        const int C = (int)min(s_candcnt, (unsigned int)CANDMAX);
        const int remT = cap - (int)s_below;    // how many to take from bucket B
        for (int i = tid; i < C; i += NTH) {
            unsigned int pv = s_cand[i];
            int less = 0;
            for (int j = 0; j < C; ++j) less += (s_cand[j] < pv) ? 1 : 0;
            if (less == remT - 1) s_P = pv;     // the remT-th smallest packed key
        }
        __syncthreads();                                       // B6
        const unsigned int P = s_P;

        // ---------- phase 5: per-thread select, scan, compact (x,y,weight) ----------
        int cs = 0;
        bool selv[EPT];
        #pragma unroll
        for (int c = 0; c < EPT; ++c) {
            const unsigned int u = ub[c];
            const unsigned int top = u >> 20;
            bool s = (top < B) ||
                     (top == B && (((u << 12) | (unsigned int)(c * NTH + tid)) <= P));
            selv[c] = s;
            cs += s ? 1 : 0;
        }
        unsigned int v2 = (unsigned int)cs;
        #pragma unroll
        for (int off = 1; off < 64; off <<= 1) {
            unsigned int o = __shfl_up(v2, off, 64);
            if (lane >= off) v2 += o;
        }
        if (lane == 63) s_wsum[wid] = v2;
        __syncthreads();                                       // B7
        unsigned int wb2 = 0;
        for (int i = 0; i < wid; ++i) wb2 += s_wsum[i];
        int wpos = (int)(v2 + wb2) - cs;
        const float dmin = s_dmin;
        float* selx = (float*)&s_hist[0];
        float* sely = (float*)&s_hist[1024];
        float* sele = (float*)&s_hist[2048];
        #pragma unroll
        for (int c = 0; c < EPT; ++c) {
            if (selv[c]) {
                float dd = __uint_as_float(ub[c]);
                selx[wpos] = wh ? ny[c] : nx[c];
                sely[wpos] = wh ? nx[c] : ny[c];
                sele[wpos] = exp2f((dmin - dd) * LOG2E);     // softmax numerator
                ++wpos;
            }
        }
        __syncthreads();                                       // B8

        // ---------- phase 6: dense mixture over the cap selected ----------
        for (int i = tid; i < cap; i += NTH) {
            const float x0 = selx[i], x1 = sely[i], e = sele[i];
            float a[NK];
            float m2 = -INFINITY;
            #pragma unroll
            for (int k = 0; k < NK; ++k) {
                float z0 = (x0 - s_mu0[k]) * s_is0[k];
                float z1 = (x1 - s_mu1[k]) * s_is1[k];
                float q  = fmaf(z0, z0, z1 * z1);
                float ak = fmaf(q, -0.5f * LOG2E, s_ck2[k]);
                a[k] = ak;
                m2 = fmaxf(m2, ak);
            }
            float se = 0.f;
            #pragma unroll
            for (int k = 0; k < NK; ++k) se += exp2f(a[k] - m2);
            float lp = LN2 * (m2 + log2f(se));
            accZ += e;
            accS += e * lp;
        }
    } else {
        __syncthreads();                 // make s_dmin visible (block-uniform branch)
        const float dmin = s_dmin;
        #pragma unroll
        for (int c = 0; c < EPT; ++c) {
            const float x0 = wh ? ny[c] : nx[c];
            const float x1 = wh ? nx[c] : ny[c];
            const float dd = __uint_as_float(ub[c]);
            const float e  = exp2f((dmin - dd) * LOG2E);
            float a[NK];
            float m2 = -INFINITY;
            #pragma unroll
            for (int k = 0; k < NK; ++k) {
                float z0 = (x0 - s_mu0[k]) * s_is0[k];
                float z1 = (x1 - s_mu1[k]) * s_is1[k];
                float q  = fmaf(z0, z0, z1 * z1);
                float ak = fmaf(q, -0.5f * LOG2E, s_ck2[k]);
                a[k] = ak;
                m2 = fmaxf(m2, ak);
            }
            float se = 0.f;
            #pragma unroll
            for (int k = 0; k < NK; ++k) se += exp2f(a[k] - m2);
            float lp = LN2 * (m2 + log2f(se));
            accZ += e;
            accS += e * lp;
        }
    }

    // ---------- block reduction of accZ / accS ----------
    #pragma unroll
    for (int off = 32; off; off >>= 1) {
        accZ += __shfl_down(accZ, off, 64);
        accS += __shfl_down(accS, off, 64);
    }
    if (lane == 0) { s_red[wid] = accZ; s_red[NWAVES + wid] = accS; }
    __syncthreads();                                           // B9
    if (tid == 0) {
        float Z = 0.f, S = 0.f;
        for (int i = 0; i < NWAVES; ++i) { Z += s_red[i]; S += s_red[NWAVES + i]; }
        rowres[row] = S / Z;
    }
}

__global__ void mdn_finalize_kernel(const float* __restrict__ rowres,
                                    float* __restrict__ out)
{
    int b = threadIdx.x;
    if (b < BS) {
        float s = 0.f;
        #pragma unroll
        for (int w = 0; w < NW; ++w) s += rowres[b * NW + w];
        out[b] = -s * (1.0f / NW);
    }
}

extern "C" void kernel_launch(void* const* d_in, const int* in_sizes, int n_in,
                              void* d_out, int out_size, void* d_ws, size_t ws_size,
                              hipStream_t stream)
{
    const float* mu    = (const float*)d_in[0];
    const float* sigma = (const float*)d_in[1];
    const float* pi    = (const float*)d_in[2];
    const float* neg   = (const float*)d_in[3];
    const float* pos   = (const float*)d_in[4];
    const int*   wh    = (const int*)d_in[5];
    const int*   cap   = (const int*)d_in[6];
    float* rowres = (float*)d_ws;   // BS*NW floats scratch
    float* out    = (float*)d_out;

    mdn_row_kernel<<<BS * NW, NTH, 0, stream>>>(mu, sigma, pi, neg, pos, wh, cap, rowres);
    mdn_finalize_kernel<<<1, 64, 0, stream>>>(rowres, out);
}